// Round 10
// baseline (629.024 us; speedup 1.0000x reference)
//
#include <hip/hip_runtime.h>
#include <hip/hip_bf16.h>

// Problem dims (fixed by setup_inputs)
#define Mdim 32
#define Kdim 8192
#define Ndim 14336
#define GSZ  128
#define NGRP 64      // Kdim / GSZ

#define KB 8         // K-split factor (blockIdx.y)
#define KC (Kdim/KB) // 1024 ints of K per block
#define BK 64        // ints per staging step (half weight-group)
#define NT (KC/BK)   // 16 staging steps
#define BN 64        // n-columns per workgroup (2 waves x 32 cols)

typedef __attribute__((ext_vector_type(16))) float f32x16;
typedef __attribute__((ext_vector_type(8)))  short bf16x8;
typedef __attribute__((ext_vector_type(4)))  int   i32x4;

typedef __attribute__((address_space(1))) const int gint_t;  // global src
typedef __attribute__((address_space(3))) int       lint_t;  // LDS dst

// ---------------------------------------------------------------------------
// Kernel 1: per-row asymmetric 8-bit quant of x -> (qx - zp) as exact bf16
// integers + per-row scale; also initializes out[row][:] = bias (atomic
// epilogue accumulates into it; d_out is re-poisoned before every launch).
// ---------------------------------------------------------------------------
__global__ __launch_bounds__(256) void quant_rows_kernel(
        const float* __restrict__ x,
        const float* __restrict__ bias,
        __hip_bfloat16* __restrict__ xq,
        float* __restrict__ scales,
        float* __restrict__ out) {
    const int row = blockIdx.x;
    const float4* __restrict__ xr4 = (const float4*)(x + (size_t)row * Kdim);

    float lmin = 3.4e38f, lmax = -3.4e38f;
#pragma unroll
    for (int i = 0; i < Kdim / 4 / 256; ++i) {           // 8 float4 per thread
        const float4 v = xr4[threadIdx.x + i * 256];
        lmin = fminf(lmin, fminf(fminf(v.x, v.y), fminf(v.z, v.w)));
        lmax = fmaxf(lmax, fmaxf(fmaxf(v.x, v.y), fmaxf(v.z, v.w)));
    }
#pragma unroll
    for (int off = 32; off > 0; off >>= 1) {
        lmin = fminf(lmin, __shfl_xor(lmin, off, 64));
        lmax = fmaxf(lmax, __shfl_xor(lmax, off, 64));
    }
    __shared__ float smin[4], smax[4];
    const int wid = threadIdx.x >> 6;
    if ((threadIdx.x & 63) == 0) { smin[wid] = lmin; smax[wid] = lmax; }
    __syncthreads();
    const float xmin = fminf(fminf(smin[0], smin[1]), fminf(smin[2], smin[3]));
    const float xmax = fmaxf(fmaxf(smax[0], smax[1]), fmaxf(smax[2], smax[3]));

    const float scale = fmaxf((xmax - xmin) / 255.0f, 1e-8f);
    float zp = rintf(-128.0f - xmin / scale);   // jnp.round == rintf (half-even)
    zp = fminf(fmaxf(zp, -128.0f), 127.0f);
    if (threadIdx.x == 0) scales[row] = scale;

    ushort4* __restrict__ xq4 = (ushort4*)(xq + (size_t)row * Kdim);
#pragma unroll
    for (int i = 0; i < Kdim / 4 / 256; ++i) {
        const float4 v = xr4[threadIdx.x + i * 256];
        ushort4 o;
        float q;
        q = fminf(fmaxf(rintf(v.x / scale) + zp, -128.0f), 127.0f);
        o.x = __bfloat16_as_ushort(__float2bfloat16(q - zp)); // exact: |.|<=255
        q = fminf(fmaxf(rintf(v.y / scale) + zp, -128.0f), 127.0f);
        o.y = __bfloat16_as_ushort(__float2bfloat16(q - zp));
        q = fminf(fmaxf(rintf(v.z / scale) + zp, -128.0f), 127.0f);
        o.z = __bfloat16_as_ushort(__float2bfloat16(q - zp));
        q = fminf(fmaxf(rintf(v.w / scale) + zp, -128.0f), 127.0f);
        o.w = __bfloat16_as_ushort(__float2bfloat16(q - zp));
        xq4[threadIdx.x + i * 256] = o;
    }

    // out[row][:] = bias
    const float4* __restrict__ b4 = (const float4*)bias;
    float4* __restrict__ o4 = (float4*)(out + (size_t)row * Ndim);
#pragma unroll
    for (int i = 0; i < Ndim / 4 / 256; ++i)             // 14 float4 per thread
        o4[threadIdx.x + i * 256] = b4[threadIdx.x + i * 256];
}

// ---------------------------------------------------------------------------
// Kernel 2: streaming GEMM, DMA-pipelined. grid = (224, 8), 128 thr (2 waves).
// Wave-private double-buffered LDS tile [32 rows][64 ints] staged with 8x
// global_load_lds (1 KB each, 4 rows x 256 B contiguous source) — no dest
// VGPRs, so the 12 issues/step stay in flight (the register batch-issue was
// sunk by the scheduler: round-8 null). Zero barriers: same-wave vmcnt(12)
// gates the reads. LDS swizzle (rule 21, both-sides): linear DMA dest +
// source chunk c^=(row&15) + read addr ^((col&15)<<4) -> 2-way conflicts.
// MFMA fragment layouts (gfx950, 32x32x16 bf16):
//   A: row = lane&31, k = 8*(lane>>5)+e
//   B: col = lane&31, k = 8*(lane>>5)+e
//   C/D: col = lane&31, row = (reg&3) + 8*(reg>>2) + 4*(lane>>5)
// ---------------------------------------------------------------------------
__global__ __launch_bounds__(128) void qlin_main_kernel(
        const int* __restrict__ qw, const float* __restrict__ wscale,
        const __hip_bfloat16* __restrict__ xq, const float* __restrict__ scales,
        float* __restrict__ out) {
    __shared__ int ldsw[2][2][32 * BK];   // [buf][wave][row*64 ints] = 32 KB

    const int lane   = threadIdx.x & 63;
    const int wid    = threadIdx.x >> 6;
    const int col31  = lane & 31;
    const int hi     = lane >> 5;
    const int colbase = blockIdx.x * BN + wid * 32;
    const int col     = colbase + col31;
    const int k0      = blockIdx.y * KC;

    // DMA source mapping: instr j covers rows 4j..4j+3, 16 lanes per row,
    // source chunk pre-swizzled so linear LDS dest ends up swizzle-stored.
    const int r_dma = lane >> 4;          // row within the 4-row quad
    const int c_dma = lane & 15;          // 16-B chunk slot within the row

    const __hip_bfloat16* __restrict__ ap =
        xq + (size_t)col31 * Kdim + k0 + hi * 8;
    const float* __restrict__ wsp = wscale + (size_t)col * NGRP + (k0 / GSZ);

    const float4 wv0 = *(const float4*)(wsp);
    const float4 wv1 = *(const float4*)(wsp + 4);
    const float wsf[8] = {wv0.x, wv0.y, wv0.z, wv0.w,
                          wv1.x, wv1.y, wv1.z, wv1.w};

    f32x16 acc = {};
    bf16x8 af[2][4];

    // ---- prologue: stage step 0 into buf0, a-frags for step 0
#pragma unroll
    for (int j = 0; j < 8; ++j) {
        const int r = 4 * j + r_dma;
        const int g = c_dma ^ (r & 15);
        const int* src = qw + (size_t)(colbase + r) * Kdim + k0 + g * 4;
        __builtin_amdgcn_global_load_lds((gint_t*)src,
                                         (lint_t*)&ldsw[0][wid][j * 256],
                                         16, 0, 0);
    }
#pragma unroll
    for (int s = 0; s < 4; ++s)
        af[0][s] = *(const bf16x8*)(ap + s * 16);

    const int swz = (col31 & 15) << 4;

#pragma unroll
    for (int gI = 0; gI < 8; ++gI) {                 // 8 weight groups
        const float ws   = wsf[gI];
        const float m8ws = -8.0f * ws;
#pragma unroll
        for (int h = 0; h < 2; ++h) {                // 2 half-groups each
            const int t = gI * 2 + h;                // compile-time (unrolled)
            if (t < NT - 1) {
                const int nt = t + 1;
                const int nb = nt & 1;
#pragma unroll
                for (int j = 0; j < 8; ++j) {
                    const int r = 4 * j + r_dma;
                    const int g = c_dma ^ (r & 15);
                    const int* src = qw + (size_t)(colbase + r) * Kdim
                                     + k0 + nt * BK + g * 4;
                    __builtin_amdgcn_global_load_lds(
                        (gint_t*)src, (lint_t*)&ldsw[nb][wid][j * 256], 16, 0, 0);
                }
#pragma unroll
                for (int s = 0; s < 4; ++s)
                    af[nb][s] = *(const bf16x8*)(ap + nt * BK + s * 16);
                // wait for step t's 12 issues (8 DMA + 4 a of last iter) to
                // complete; the 12 just issued stay in flight across compute.
                asm volatile("s_waitcnt vmcnt(12)" ::: "memory");
            } else {
                asm volatile("s_waitcnt vmcnt(0)" ::: "memory");
            }
            __builtin_amdgcn_sched_barrier(0);

            const int cb = t & 1;
            const char* wbase =
                (const char*)&ldsw[cb][wid][0] + col31 * (BK * 4);
#pragma unroll
            for (int s = 0; s < 4; ++s) {            // 4 MFMA K-steps
                const int b0 = ((s << 6) | (hi << 5)) ^ swz;
                const i32x4 q0 = *(const i32x4*)(wbase + b0);
                const i32x4 q1 = *(const i32x4*)(wbase + (b0 ^ 16));

                union { bf16x8 v; __hip_bfloat162 h2[4]; } bu;
                const float f0 = fmaf((float)q0[0], ws, m8ws);
                const float f1 = fmaf((float)q0[1], ws, m8ws);
                const float f2 = fmaf((float)q0[2], ws, m8ws);
                const float f3 = fmaf((float)q0[3], ws, m8ws);
                const float f4 = fmaf((float)q1[0], ws, m8ws);
                const float f5 = fmaf((float)q1[1], ws, m8ws);
                const float f6 = fmaf((float)q1[2], ws, m8ws);
                const float f7 = fmaf((float)q1[3], ws, m8ws);
                bu.h2[0] = __float22bfloat162_rn(float2{f0, f1});
                bu.h2[1] = __float22bfloat162_rn(float2{f2, f3});
                bu.h2[2] = __float22bfloat162_rn(float2{f4, f5});
                bu.h2[3] = __float22bfloat162_rn(float2{f6, f7});

                acc = __builtin_amdgcn_mfma_f32_32x32x16_bf16(
                    af[cb][s], bu.v, acc, 0, 0, 0);
            }
        }
    }

    // Epilogue: out[row][col] += scale_row * acc  (8-way K-split atomics;
    // measured cheaper than partials+reduce in rounds 2/3)
    const int rbase = hi * 4;
    const float4 s0 = *(const float4*)(scales + rbase);
    const float4 s1 = *(const float4*)(scales + rbase + 8);
    const float4 s2 = *(const float4*)(scales + rbase + 16);
    const float4 s3 = *(const float4*)(scales + rbase + 24);
    const float sr[16] = {s0.x, s0.y, s0.z, s0.w, s1.x, s1.y, s1.z, s1.w,
                          s2.x, s2.y, s2.z, s2.w, s3.x, s3.y, s3.z, s3.w};
#pragma unroll
    for (int r = 0; r < 16; ++r) {
        const int row = (r & 3) + 8 * (r >> 2) + rbase;
        unsafeAtomicAdd(out + (size_t)row * Ndim + col, sr[r] * acc[r]);
    }
}

// ---------------------------------------------------------------------------
extern "C" void kernel_launch(void* const* d_in, const int* in_sizes, int n_in,
                              void* d_out, int out_size, void* d_ws, size_t ws_size,
                              hipStream_t stream) {
    const float* x    = (const float*)d_in[0];
    const int*   qw   = (const int*)d_in[1];
    const float* wsc  = (const float*)d_in[2];
    const float* bias = (const float*)d_in[3];
    float* out = (float*)d_out;

    // ws layout: [0,128): row scales (32 f32); [256, 256+512K): xq bf16
    float* scales = (float*)d_ws;
    __hip_bfloat16* xq = (__hip_bfloat16*)((char*)d_ws + 256);

    quant_rows_kernel<<<Mdim, 256, 0, stream>>>(x, bias, xq, scales, out);
    qlin_main_kernel<<<dim3(Ndim / BN, KB), 128, 0, stream>>>(qw, wsc, xq, scales, out);
}